// Round 5
// baseline (605.756 us; speedup 1.0000x reference)
//
#include <hip/hip_runtime.h>

constexpr int N_ = 4096, C_ = 32, CN_ = 64, M_ = 64;
constexpr int TPB = 256;
constexpr int RPT = 12, LPT = 4;          // reg / LDS points per thread
constexpr int NREG = RPT * TPB;           // 3072
constexpr int NLDS = LPT * TPB;           // 1024
constexpr int LSTR = NLDS + 1;            // padded LDS stride (bank-conflict-free)

// ---------------- kernel 0: per-point squared norms in metric G_r ----------------
// blk = (b*3+r)*16 + chunk ; r=0: G=I (events), r=1: G=Wk^T Wk, r=2: G=Wv^T Wv
__global__ void norms_kernel(const float* __restrict__ ev,
                             const float* __restrict__ Wk,
                             const float* __restrict__ Wv,
                             float* __restrict__ nrm_all) {
  int blk = blockIdx.x;
  int chunk = blk & 15, br = blk >> 4;
  int r = br % 3;
  int b = br / 3;
  __shared__ float G[C_][C_ + 1];
  const float* W = (r == 1) ? Wk : Wv;
  for (int e = threadIdx.x; e < C_ * C_; e += TPB) {
    int a = e >> 5, d = e & 31;
    float g;
    if (r == 0) {
      g = (a == d) ? 1.f : 0.f;
    } else {
      double acc = 0.0;
      for (int q = 0; q < CN_; ++q)
        acc += (double)W[q * C_ + a] * (double)W[q * C_ + d];
      g = (float)acc;
    }
    G[a][d] = g;
  }
  __syncthreads();
  int p = chunk * TPB + threadIdx.x;
  const float4* row = (const float4*)(ev + (size_t)b * N_ * C_ + (size_t)p * C_);
  float x[C_];
#pragma unroll
  for (int q = 0; q < C_ / 4; ++q) {
    float4 v = row[q];
    x[q * 4 + 0] = v.x; x[q * 4 + 1] = v.y; x[q * 4 + 2] = v.z; x[q * 4 + 3] = v.w;
  }
  double n = 0.0;
#pragma unroll
  for (int a = 0; a < C_; ++a) {
    double ta = 0.0;
#pragma unroll
    for (int d = 0; d < C_; ++d) ta += (double)G[a][d] * (double)x[d];
    n += ta * (double)x[a];
  }
  nrm_all[(size_t)br * N_ + p] = (float)n;
}

// ---------------- kernel 1: farthest point sampling (one block per (batch,run)) ----------------
__global__ __launch_bounds__(TPB, 1) void fps_kernel(
    const float* __restrict__ ev, const float* __restrict__ Wk,
    const float* __restrict__ Wv, const float* __restrict__ nrm_all,
    int* __restrict__ idx_ws, float* __restrict__ sum_ws) {
  const int t = threadIdx.x;
  const int blk = blockIdx.x;          // b*3 + r
  const int b = blk / 3, r = blk % 3;
  const float* evb = ev + (size_t)b * N_ * C_;
  const float* nrm = nrm_all + (size_t)blk * N_;

  __shared__ float G[C_][C_ + 1];
  __shared__ float LP[C_][LSTR];       // transposed LDS-resident points [dim][col]
  __shared__ float LN[NLDS];
  __shared__ float yv[C_];
  __shared__ float cf[C_];             // current centroid features
  __shared__ float redV[TPB / 64];
  __shared__ int   redI[TPB / 64];
  __shared__ float msum[TPB / 64][C_];
  __shared__ float curN_s;
  __shared__ int   jsel_s;

  // ---- metric G ----
  {
    const float* W = (r == 1) ? Wk : Wv;
    for (int e = t; e < C_ * C_; e += TPB) {
      int a = e >> 5, d = e & 31;
      float g;
      if (r == 0) g = (a == d) ? 1.f : 0.f;
      else {
        double acc = 0.0;
        for (int q = 0; q < CN_; ++q)
          acc += (double)W[q * C_ + a] * (double)W[q * C_ + d];
        g = (float)acc;
      }
      G[a][d] = g;
    }
  }

  // ---- load points (12 in regs, 4 in LDS per thread) + mean partials ----
  float px[RPT][C_], pn[RPT], dmin[RPT];
  float nl[LPT], dminL[LPT];
  {
    float accsum[C_];
#pragma unroll
    for (int d = 0; d < C_; ++d) accsum[d] = 0.f;
#pragma unroll
    for (int j = 0; j < RPT; ++j) {
      int p = j * TPB + t;
      const float4* row = (const float4*)(evb + (size_t)p * C_);
#pragma unroll
      for (int q = 0; q < C_ / 4; ++q) {
        float4 v = row[q];
        px[j][q * 4 + 0] = v.x; px[j][q * 4 + 1] = v.y;
        px[j][q * 4 + 2] = v.z; px[j][q * 4 + 3] = v.w;
      }
      pn[j] = nrm[p];
#pragma unroll
      for (int d = 0; d < C_; ++d) accsum[d] += px[j][d];
    }
#pragma unroll
    for (int i = 0; i < LPT; ++i) {
      int col = i * TPB + t;
      int p = NREG + col;
      const float4* row = (const float4*)(evb + (size_t)p * C_);
#pragma unroll
      for (int q = 0; q < C_ / 4; ++q) {
        float4 v = row[q];
        LP[q * 4 + 0][col] = v.x; LP[q * 4 + 1][col] = v.y;
        LP[q * 4 + 2][col] = v.z; LP[q * 4 + 3][col] = v.w;
        accsum[q * 4 + 0] += v.x; accsum[q * 4 + 1] += v.y;
        accsum[q * 4 + 2] += v.z; accsum[q * 4 + 3] += v.w;
      }
      nl[i] = nrm[p];
      LN[col] = nrm[p];
    }
    // block-wide sum per dim
#pragma unroll
    for (int d = 0; d < C_; ++d) {
      float s = accsum[d];
#pragma unroll
      for (int off = 32; off; off >>= 1) s += __shfl_xor(s, off);
      if ((t & 63) == 0) msum[t >> 6][d] = s;
    }
  }
  __syncthreads();
  if (t < C_) {
    float tot = msum[0][t] + msum[1][t] + msum[2][t] + msum[3][t];
    if (r == 0) sum_ws[b * C_ + t] = tot;     // Σ_n ev (for P in finalize)
    cf[t] = tot * (1.f / (float)N_);          // barycenter
  }
  __syncthreads();
  // y = G*cf (f64 accum), curN = cf·y  (barycenter round)
  if (t < C_) {
    double acc = 0.0;
#pragma unroll
    for (int d = 0; d < C_; ++d) acc += (double)G[t][d] * (double)cf[d];
    yv[t] = (float)acc;
  }
  __syncthreads();
  if (t == 0) {
    float acc = 0.f;
    for (int d = 0; d < C_; ++d) acc += cf[d] * yv[d];
    curN_s = acc;
  }
#pragma unroll
  for (int j = 0; j < RPT; ++j) dmin[j] = 1e10f;
#pragma unroll
  for (int i = 0; i < LPT; ++i) dminL[i] = 1e10f;
  __syncthreads();

  auto eval_round = [&](bool update) {
    float curN = curN_s;
    float bv = -3e38f; int bi = 0x7fffffff;
    float acc[RPT], accL[LPT];
#pragma unroll
    for (int j = 0; j < RPT; ++j) acc[j] = 0.f;
#pragma unroll
    for (int i = 0; i < LPT; ++i) accL[i] = 0.f;
#pragma unroll
    for (int dc = 0; dc < C_; dc += 8) {
      float yc[8];
#pragma unroll
      for (int q = 0; q < 8; ++q) yc[q] = yv[dc + q];
#pragma unroll
      for (int j = 0; j < RPT; ++j) {
#pragma unroll
        for (int q = 0; q < 8; ++q) acc[j] = fmaf(px[j][dc + q], yc[q], acc[j]);
      }
#pragma unroll
      for (int i = 0; i < LPT; ++i) {
        int col = i * TPB + t;
#pragma unroll
        for (int q = 0; q < 8; ++q) accL[i] = fmaf(LP[dc + q][col], yc[q], accL[i]);
      }
    }
#pragma unroll
    for (int j = 0; j < RPT; ++j) {
      float d = pn[j] - 2.f * acc[j] + curN;
      float v;
      if (update) { dmin[j] = fminf(dmin[j], d); v = dmin[j]; }
      else v = d;
      int p = j * TPB + t;
      if (v > bv) { bv = v; bi = p; }
    }
#pragma unroll
    for (int i = 0; i < LPT; ++i) {
      float d = nl[i] - 2.f * accL[i] + curN;
      float v;
      if (update) { dminL[i] = fminf(dminL[i], d); v = dminL[i]; }
      else v = d;
      int p = NREG + i * TPB + t;
      if (v > bv) { bv = v; bi = p; }
    }
    // argmax, lowest-index tie-break (matches jnp.argmax first-max semantics)
#pragma unroll
    for (int off = 1; off < 64; off <<= 1) {
      float ov = __shfl_xor(bv, off);
      int   oi = __shfl_xor(bi, off);
      if (ov > bv || (ov == bv && oi < bi)) { bv = ov; bi = oi; }
    }
    if ((t & 63) == 0) { redV[t >> 6] = bv; redI[t >> 6] = bi; }
    __syncthreads();
    if (t == 0) {
      float fv = redV[0]; int fi = redI[0];
      for (int w = 1; w < TPB / 64; ++w)
        if (redV[w] > fv || (redV[w] == fv && redI[w] < fi)) { fv = redV[w]; fi = redI[w]; }
      jsel_s = fi;
    }
    __syncthreads();
  };

  eval_round(false);   // pick f0 from barycenter distances (no dmin update)

  for (int it = 0; it < M_; ++it) {
    int jsel = jsel_s;
    if (t == 0) idx_ws[blk * M_ + it] = jsel;
    if (jsel < NREG) {
#pragma unroll
      for (int j = 0; j < RPT; ++j) {
        if (jsel == j * TPB + t) {
#pragma unroll
          for (int d = 0; d < C_; ++d) cf[d] = px[j][d];
          curN_s = pn[j];
          dmin[j] = -3e38f;          // never re-select
        }
      }
    } else {
#pragma unroll
      for (int i = 0; i < LPT; ++i)
        if (jsel == NREG + i * TPB + t) dminL[i] = -3e38f;
      int col = jsel - NREG;
      if (t < C_) cf[t] = LP[t][col];
      if (t == 0) curN_s = LN[col];
    }
    __syncthreads();
    if (it == M_ - 1) break;
    if (t < C_) {
      double acc = 0.0;
#pragma unroll
      for (int d = 0; d < C_; ++d) acc += (double)G[t][d] * (double)cf[d];
      yv[t] = (float)acc;
    }
    __syncthreads();
    eval_round(true);
  }
}

// ---------------- kernel 2: finalize (one block of 64 threads per batch) ----------------
// CRITICAL: fps() returns selections in ASCENDING ORIGINAL-INDEX order
// (masked_select semantics). Each of the three FPS runs must be
// independently index-sorted BEFORE zipping along the m axis, because
// logits pairs k_m[m] with pe_m[m] (ev run) and S pairs v_m[m] with
// pe_m[m]. Selection-order pairing scrambles these triples.
__global__ void finalize_kernel(
    const float* __restrict__ ev, const float* __restrict__ Wk,
    const float* __restrict__ Wv, const float* __restrict__ Wpe,
    const float* __restrict__ Wsa1, const float* __restrict__ Wsa2,
    const int* __restrict__ idx_ws, const float* __restrict__ sum_ws,
    float* __restrict__ outvec_ws) {
  const int b = blockIdx.x;
  const int m = threadIdx.x;           // 64 threads = 64 selected slots
  const float* evb = ev + (size_t)b * N_ * C_;

  // ---- rank-sort each run's 64 indices ascending ----
  __shared__ int le[M_], lk[M_], lv[M_];
  __shared__ int se[M_], sk[M_], sv[M_];
  int my_e = idx_ws[(b * 3 + 0) * M_ + m];
  int my_k = idx_ws[(b * 3 + 1) * M_ + m];
  int my_v = idx_ws[(b * 3 + 2) * M_ + m];
  le[m] = my_e; lk[m] = my_k; lv[m] = my_v;
  __syncthreads();
  int re = 0, rk = 0, rv = 0;
#pragma unroll
  for (int j = 0; j < M_; ++j) {
    re += (le[j] < my_e) || (le[j] == my_e && j < m);
    rk += (lk[j] < my_k) || (lk[j] == my_k && j < m);
    rv += (lv[j] < my_v) || (lv[j] == my_v && j < m);
  }
  se[re] = my_e; sk[rk] = my_k; sv[rv] = my_v;
  __syncthreads();
  int ie = se[m];    // m-th smallest-index ev-FPS selection
  int ik = sk[m];    // m-th smallest-index k-FPS selection
  int iv = sv[m];    // m-th smallest-index v-FPS selection

  float xe[C_], xk[C_], xv[C_];
#pragma unroll
  for (int c = 0; c < C_; ++c) {
    xe[c] = evb[(size_t)ie * C_ + c];
    xk[c] = evb[(size_t)ik * C_ + c];
    xv[c] = evb[(size_t)iv * C_ + c];
  }
  float pe[CN_], km[CN_], vm[CN_];
#pragma unroll 4
  for (int cn = 0; cn < CN_; ++cn) {
    float a1 = 0.f, a2 = 0.f, a3 = 0.f;
#pragma unroll
    for (int c = 0; c < C_; ++c) {
      a1 = fmaf(xe[c], Wpe[cn * C_ + c], a1);
      a2 = fmaf(xk[c], Wk[cn * C_ + c], a2);
      a3 = fmaf(xv[c], Wv[cn * C_ + c], a3);
    }
    pe[cn] = a1; km[cn] = a2; vm[cn] = a3;
  }
  __shared__ float Pl[CN_];
  {
    float a = 0.f;
#pragma unroll
    for (int c = 0; c < C_; ++c) a = fmaf(sum_ws[b * C_ + c], Wpe[m * C_ + c], a);
    Pl[m] = a;                 // P[cn] = (Σ_n ev) @ Wpe^T, thread m computes cn=m
  }
  float cm = 0.f;
#pragma unroll
  for (int cn = 0; cn < CN_; ++cn) cm = fmaf(km[cn] + pe[cn], Wsa1[cn], cm);
  float lg = -cm;
  float mx = lg;
#pragma unroll
  for (int off = 32; off; off >>= 1) mx = fmaxf(mx, __shfl_xor(mx, off));
  float e = expf(lg - mx);
  float ssum = e;
#pragma unroll
  for (int off = 32; off; off >>= 1) ssum += __shfl_xor(ssum, off);
  float s = e / ssum;
  __shared__ float tmp[CN_][CN_ + 1];
  __syncthreads();   // Pl ready
#pragma unroll
  for (int cn = 0; cn < CN_; ++cn)
    tmp[m][cn] = s * (fmaf((float)N_, vm[cn], Pl[cn]) - (float)N_ * pe[cn]);
  __syncthreads();
  float tv = 0.f;
#pragma unroll
  for (int mm = 0; mm < CN_; ++mm) tv += tmp[mm][m];
  __shared__ float tvec[CN_];
  tvec[m] = tv;
  __syncthreads();
  if (m < C_) {
    float o = 0.f;
#pragma unroll
    for (int cn = 0; cn < CN_; ++cn) o = fmaf(tvec[cn], Wsa2[m * CN_ + cn], o);
    outvec_ws[b * C_ + m] = o;
  }
}

// ---------------- kernel 3: broadcast out[b][n][:] = outvec[b][:] ----------------
__global__ void bcast_kernel(const float* __restrict__ outvec_ws,
                             float4* __restrict__ out) {
  int i = blockIdx.x * TPB + threadIdx.x;   // < 4*4096*8
  int b = i >> 15;
  int j = i & 7;
  const float4* ov = (const float4*)outvec_ws;
  out[i] = ov[b * 8 + j];
}

extern "C" void kernel_launch(void* const* d_in, const int* in_sizes, int n_in,
                              void* d_out, int out_size, void* d_ws, size_t ws_size,
                              hipStream_t stream) {
  const float* ev   = (const float*)d_in[0];
  // d_in[1] = W_qs: provably unused (a_n cancels in softmax over m)
  const float* Wk   = (const float*)d_in[2];
  const float* Wv   = (const float*)d_in[3];
  const float* Wpe  = (const float*)d_in[4];
  const float* Wsa1 = (const float*)d_in[5];
  const float* Wsa2 = (const float*)d_in[6];
  float* out = (float*)d_out;

  char* ws = (char*)d_ws;
  int*   idx    = (int*)ws;                    // 12*64*4     = 3072 B
  float* sumev  = (float*)(ws + 3072);         // 4*32*4      = 512 B
  float* outvec = (float*)(ws + 3584);         // 4*32*4      = 512 B
  float* nrm    = (float*)(ws + 4096);         // 12*4096*4   = 196608 B

  norms_kernel   <<<dim3(192), dim3(TPB), 0, stream>>>(ev, Wk, Wv, nrm);
  fps_kernel     <<<dim3(12),  dim3(TPB), 0, stream>>>(ev, Wk, Wv, nrm, idx, sumev);
  finalize_kernel<<<dim3(4),   dim3(64),  0, stream>>>(ev, Wk, Wv, Wpe, Wsa1, Wsa2,
                                                       idx, sumev, outvec);
  bcast_kernel   <<<dim3(512), dim3(TPB), 0, stream>>>(outvec, (float4*)out);
}

// Round 6
// 395.457 us; speedup vs baseline: 1.5318x; 1.5318x over previous
//
#include <hip/hip_runtime.h>

constexpr int N_ = 4096, C_ = 32, CN_ = 64, M_ = 64;
constexpr int TPB = 512;              // fps block: 8 waves, 2/SIMD
constexpr int RPT = 6, LPT = 2;       // reg / LDS points per thread
constexpr int NREG = RPT * TPB;       // 3072
constexpr int NLDS = LPT * TPB;       // 1024
constexpr int NTPB = 256;             // norms block
constexpr int NCHUNK = N_ / NTPB;     // 16

// ---------------- kernel 0: per-point z = G·x (f64 accum) + norms + Σx partials ----------------
// blk = (b*3+r)*16 + chunk ; r=0: G=I, r=1: G=Wk^T Wk, r=2: G=Wv^T Wv
__global__ void norms_kernel(const float* __restrict__ ev,
                             const float* __restrict__ Wk,
                             const float* __restrict__ Wv,
                             float* __restrict__ nrm_all,
                             float* __restrict__ zall,
                             float* __restrict__ partials) {
  int blk = blockIdx.x;
  int chunk = blk & (NCHUNK - 1), br = blk >> 4;
  int r = br % 3, b = br / 3;
  int t = threadIdx.x;
  __shared__ float G[C_][C_ + 1];
  const float* W = (r == 1) ? Wk : Wv;
  for (int e = t; e < C_ * C_; e += NTPB) {
    int a = e >> 5, d = e & 31;
    float g;
    if (r == 0) {
      g = (a == d) ? 1.f : 0.f;
    } else {
      double acc = 0.0;
      for (int q = 0; q < CN_; ++q)
        acc += (double)W[q * C_ + a] * (double)W[q * C_ + d];
      g = (float)acc;
    }
    G[a][d] = g;
  }
  __syncthreads();
  int p = chunk * NTPB + t;
  const float4* row = (const float4*)(ev + ((size_t)b * N_ + p) * C_);
  float x[C_];
#pragma unroll
  for (int q = 0; q < C_ / 4; ++q) {
    float4 v = row[q];
    x[q * 4 + 0] = v.x; x[q * 4 + 1] = v.y; x[q * 4 + 2] = v.z; x[q * 4 + 3] = v.w;
  }
  double n = 0.0;
  float z[C_];
#pragma unroll
  for (int a = 0; a < C_; ++a) {
    double ta = 0.0;
#pragma unroll
    for (int d = 0; d < C_; ++d) ta += (double)G[a][d] * (double)x[d];
    z[a] = (float)ta;
    n += ta * (double)x[a];
  }
  nrm_all[(size_t)br * N_ + p] = (float)n;
  float4* zrow = (float4*)(zall + ((size_t)br * N_ + p) * C_);
#pragma unroll
  for (int q = 0; q < C_ / 4; ++q)
    zrow[q] = make_float4(z[q * 4 + 0], z[q * 4 + 1], z[q * 4 + 2], z[q * 4 + 3]);

  if (r == 0) {   // deterministic per-chunk Σx partials (no atomics)
    __shared__ float msum[NTPB / 64][C_];
#pragma unroll
    for (int d = 0; d < C_; ++d) {
      float s = x[d];
#pragma unroll
      for (int off = 32; off; off >>= 1) s += __shfl_xor(s, off);
      if ((t & 63) == 0) msum[t >> 6][d] = s;
    }
    __syncthreads();
    if (t < C_)
      partials[((size_t)b * NCHUNK + chunk) * C_ + t] =
          msum[0][t] + msum[1][t] + msum[2][t] + msum[3][t];
  }
}

// ---------------- kernel 1: FPS — one block per (batch,run), z-metric ----------------
// d(i, sel) = n_i - 2 * z_i · x_sel + n_sel    (G symmetric: x_i·G·c = z_i·c)
__global__ __launch_bounds__(TPB, 2) void fps_kernel(
    const float* __restrict__ ev, const float* __restrict__ nrm_all,
    const float* __restrict__ zall, const float* __restrict__ partials,
    int* __restrict__ idx_ws) {
  const int t = threadIdx.x;
  const int blk = blockIdx.x;          // b*3 + r
  const int b = blk / 3;
  const float* evb = ev + (size_t)b * N_ * C_;
  const float* nrm = nrm_all + (size_t)blk * N_;
  const float4* zb4 = (const float4*)(zall + (size_t)blk * N_ * C_);

  __shared__ float LP[NLDS * C_];      // swizzled z rows of pts 3072..4095 (128 KB)
  __shared__ float cf0[C_];            // barycenter (round 0 only)
  __shared__ float redV[2][TPB / 64];
  __shared__ int   redI[2][TPB / 64];

  float z[RPT][C_], pn[RPT], dmin[RPT];
  float nl[LPT], dminL[LPT];

  // ---- load reg z-points ----
#pragma unroll
  for (int j = 0; j < RPT; ++j) {
    int p = j * TPB + t;
#pragma unroll
    for (int q = 0; q < C_ / 4; ++q) {
      float4 v = zb4[(size_t)p * 8 + q];
      z[j][q * 4 + 0] = v.x; z[j][q * 4 + 1] = v.y;
      z[j][q * 4 + 2] = v.z; z[j][q * 4 + 3] = v.w;
    }
    pn[j] = nrm[p];
    dmin[j] = 1e10f;
  }
  // ---- stage LDS z-points, XOR-quad swizzle (conflict-free b128) ----
#pragma unroll
  for (int i = 0; i < LPT; ++i) {
    int col = i * TPB + t;
    int p = NREG + col;
#pragma unroll
    for (int q = 0; q < C_ / 4; ++q) {
      float4 v = zb4[(size_t)p * 8 + q];
      int off = (col << 5) + ((q ^ (col & 7)) << 2);
      *(float4*)&LP[off] = v;
    }
    nl[i] = nrm[p];
    dminL[i] = 1e10f;
  }
  // ---- barycenter from partials (deterministic) ----
  if (t < C_) {
    float s = 0.f;
#pragma unroll
    for (int c = 0; c < NCHUNK; ++c) s += partials[((size_t)b * NCHUNK + c) * C_ + t];
    cf0[t] = s * (1.f / (float)N_);
  }
  __syncthreads();   // LP + cf0 ready

  auto eval = [&](const float* __restrict__ cf, float curN, bool update,
                  float& bv, int& bi) {
    float acc[RPT], accL[LPT];
#pragma unroll
    for (int j = 0; j < RPT; ++j) acc[j] = 0.f;
#pragma unroll
    for (int i = 0; i < LPT; ++i) accL[i] = 0.f;
    const float4* cf4 = (const float4*)cf;
#pragma unroll
    for (int q = 0; q < C_ / 4; ++q) {
      float4 c = cf4[q];
#pragma unroll
      for (int j = 0; j < RPT; ++j) {
        acc[j] = fmaf(z[j][q * 4 + 0], c.x, acc[j]);
        acc[j] = fmaf(z[j][q * 4 + 1], c.y, acc[j]);
        acc[j] = fmaf(z[j][q * 4 + 2], c.z, acc[j]);
        acc[j] = fmaf(z[j][q * 4 + 3], c.w, acc[j]);
      }
#pragma unroll
      for (int i = 0; i < LPT; ++i) {
        int col = i * TPB + t;
        int off = (col << 5) + ((q ^ (col & 7)) << 2);
        float4 l = *(const float4*)&LP[off];
        accL[i] = fmaf(l.x, c.x, fmaf(l.y, c.y, fmaf(l.z, c.z, fmaf(l.w, c.w, accL[i]))));
      }
    }
    bv = -3e38f; bi = 0x7fffffff;
#pragma unroll
    for (int j = 0; j < RPT; ++j) {
      float d = fmaf(-2.f, acc[j], pn[j]) + curN;
      float v;
      if (update) { dmin[j] = fminf(dmin[j], d); v = dmin[j]; }
      else v = d;
      int p = j * TPB + t;
      if (v > bv) { bv = v; bi = p; }
    }
#pragma unroll
    for (int i = 0; i < LPT; ++i) {
      float d = fmaf(-2.f, accL[i], nl[i]) + curN;
      float v;
      if (update) { dminL[i] = fminf(dminL[i], d); v = dminL[i]; }
      else v = d;
      int p = NREG + i * TPB + t;
      if (v > bv) { bv = v; bi = p; }
    }
    // wave argmax, lowest-index tie-break (jnp.argmax first-max semantics)
#pragma unroll
    for (int off = 1; off < 64; off <<= 1) {
      float ov = __shfl_xor(bv, off);
      int   oi = __shfl_xor(bi, off);
      if (ov > bv || (ov == bv && oi < bi)) { bv = ov; bi = oi; }
    }
  };

  // ---- round 0: barycenter (curN shift irrelevant for argmax; no dmin update) ----
  {
    float bv; int bi;
    eval(cf0, 0.f, false, bv, bi);
    if ((t & 63) == 0) { redV[0][t >> 6] = bv; redI[0][t >> 6] = bi; }
  }
  __syncthreads();

  // ---- main loop: 1 barrier per iteration, double-buffered reduce slots ----
  for (int it = 0; it < M_; ++it) {
    int rb = it & 1;
    // every thread redundantly scans the 8 wave entries -> identical jsel
    float fv = redV[rb][0]; int fi = redI[rb][0];
#pragma unroll
    for (int w = 1; w < TPB / 64; ++w) {
      float wv = redV[rb][w]; int wi = redI[rb][w];
      if (wv > fv || (wv == fv && wi < fi)) { fv = wv; fi = wi; }
    }
    int jsel = fi;
    if (t == 0) idx_ws[blk * M_ + it] = jsel;
    // owner kills its dmin slot (never re-select)
    if (jsel < NREG) {
      int j = jsel >> 9, tt = jsel & (TPB - 1);
      if (t == tt) dmin[j] = -3e38f;
    } else {
      int col = jsel - NREG;
      int i = col >> 9, tt = col & (TPB - 1);
      if (t == tt) dminL[i] = -3e38f;
    }
    if (it == M_ - 1) break;
    float curN = nrm[jsel];                       // broadcast global load
    const float* cf = evb + (size_t)jsel * C_;    // raw features of selected point
    float bv; int bi;
    eval(cf, curN, true, bv, bi);
    if ((t & 63) == 0) { redV[rb ^ 1][t >> 6] = bv; redI[rb ^ 1][t >> 6] = bi; }
    __syncthreads();
  }
}

// ---------------- kernel 2: finalize (one block of 64 threads per batch) ----------------
// fps() returns selections in ASCENDING ORIGINAL-INDEX order (masked_select);
// rank-sort each run's indices before zipping along m (pairing matters).
__global__ void finalize_kernel(
    const float* __restrict__ ev, const float* __restrict__ Wk,
    const float* __restrict__ Wv, const float* __restrict__ Wpe,
    const float* __restrict__ Wsa1, const float* __restrict__ Wsa2,
    const int* __restrict__ idx_ws, const float* __restrict__ partials,
    float* __restrict__ outvec_ws) {
  const int b = blockIdx.x;
  const int m = threadIdx.x;           // 64 threads = 64 selected slots
  const float* evb = ev + (size_t)b * N_ * C_;

  __shared__ int le[M_], lk[M_], lv[M_];
  __shared__ int se[M_], sk[M_], sv[M_];
  __shared__ float sumx[C_];
  int my_e = idx_ws[(b * 3 + 0) * M_ + m];
  int my_k = idx_ws[(b * 3 + 1) * M_ + m];
  int my_v = idx_ws[(b * 3 + 2) * M_ + m];
  le[m] = my_e; lk[m] = my_k; lv[m] = my_v;
  if (m < C_) {
    float s = 0.f;
#pragma unroll
    for (int c = 0; c < NCHUNK; ++c) s += partials[((size_t)b * NCHUNK + c) * C_ + m];
    sumx[m] = s;
  }
  __syncthreads();
  int re = 0, rk = 0, rv = 0;
#pragma unroll
  for (int j = 0; j < M_; ++j) {
    re += (le[j] < my_e) || (le[j] == my_e && j < m);
    rk += (lk[j] < my_k) || (lk[j] == my_k && j < m);
    rv += (lv[j] < my_v) || (lv[j] == my_v && j < m);
  }
  se[re] = my_e; sk[rk] = my_k; sv[rv] = my_v;
  __syncthreads();
  int ie = se[m], ik = sk[m], iv = sv[m];

  float xe[C_], xk[C_], xv[C_];
#pragma unroll
  for (int c = 0; c < C_; ++c) {
    xe[c] = evb[(size_t)ie * C_ + c];
    xk[c] = evb[(size_t)ik * C_ + c];
    xv[c] = evb[(size_t)iv * C_ + c];
  }
  float pe[CN_], km[CN_], vm[CN_];
#pragma unroll 4
  for (int cn = 0; cn < CN_; ++cn) {
    float a1 = 0.f, a2 = 0.f, a3 = 0.f;
#pragma unroll
    for (int c = 0; c < C_; ++c) {
      a1 = fmaf(xe[c], Wpe[cn * C_ + c], a1);
      a2 = fmaf(xk[c], Wk[cn * C_ + c], a2);
      a3 = fmaf(xv[c], Wv[cn * C_ + c], a3);
    }
    pe[cn] = a1; km[cn] = a2; vm[cn] = a3;
  }
  __shared__ float Pl[CN_];
  {
    float a = 0.f;
#pragma unroll
    for (int c = 0; c < C_; ++c) a = fmaf(sumx[c], Wpe[m * C_ + c], a);
    Pl[m] = a;                 // P[cn] = (Σ_n ev) @ Wpe^T
  }
  float cm = 0.f;
#pragma unroll
  for (int cn = 0; cn < CN_; ++cn) cm = fmaf(km[cn] + pe[cn], Wsa1[cn], cm);
  float lg = -cm;
  float mx = lg;
#pragma unroll
  for (int off = 32; off; off >>= 1) mx = fmaxf(mx, __shfl_xor(mx, off));
  float e = expf(lg - mx);
  float ssum = e;
#pragma unroll
  for (int off = 32; off; off >>= 1) ssum += __shfl_xor(ssum, off);
  float s = e / ssum;
  __shared__ float tmp[CN_][CN_ + 1];
  __syncthreads();   // Pl ready
#pragma unroll
  for (int cn = 0; cn < CN_; ++cn)
    tmp[m][cn] = s * (fmaf((float)N_, vm[cn], Pl[cn]) - (float)N_ * pe[cn]);
  __syncthreads();
  float tv = 0.f;
#pragma unroll
  for (int mm = 0; mm < CN_; ++mm) tv += tmp[mm][m];
  __shared__ float tvec[CN_];
  tvec[m] = tv;
  __syncthreads();
  if (m < C_) {
    float o = 0.f;
#pragma unroll
    for (int cn = 0; cn < CN_; ++cn) o = fmaf(tvec[cn], Wsa2[m * CN_ + cn], o);
    outvec_ws[b * C_ + m] = o;
  }
}

// ---------------- kernel 3: broadcast out[b][n][:] = outvec[b][:] ----------------
__global__ void bcast_kernel(const float* __restrict__ outvec_ws,
                             float4* __restrict__ out) {
  int i = blockIdx.x * 256 + threadIdx.x;   // < 4*4096*8
  int b = i >> 15;
  int j = i & 7;
  const float4* ov = (const float4*)outvec_ws;
  out[i] = ov[b * 8 + j];
}

extern "C" void kernel_launch(void* const* d_in, const int* in_sizes, int n_in,
                              void* d_out, int out_size, void* d_ws, size_t ws_size,
                              hipStream_t stream) {
  const float* ev   = (const float*)d_in[0];
  // d_in[1] = W_qs: provably unused (a_n cancels in softmax over m)
  const float* Wk   = (const float*)d_in[2];
  const float* Wv   = (const float*)d_in[3];
  const float* Wpe  = (const float*)d_in[4];
  const float* Wsa1 = (const float*)d_in[5];
  const float* Wsa2 = (const float*)d_in[6];
  float* out = (float*)d_out;

  char* ws = (char*)d_ws;
  int*   idx    = (int*)ws;                     // 12*64*4        = 3072 B
  float* parts  = (float*)(ws + 3072);          // 4*16*32*4      = 8192 B
  float* outvec = (float*)(ws + 11264);         // 4*32*4         = 512 B
  float* nrm    = (float*)(ws + 11776);         // 12*4096*4      = 196608 B
  float* zall   = (float*)(ws + 208384);        // 12*4096*32*4   = 6291456 B

  norms_kernel   <<<dim3(192), dim3(NTPB), 0, stream>>>(ev, Wk, Wv, nrm, zall, parts);
  fps_kernel     <<<dim3(12),  dim3(TPB),  0, stream>>>(ev, nrm, zall, parts, idx);
  finalize_kernel<<<dim3(4),   dim3(64),   0, stream>>>(ev, Wk, Wv, Wpe, Wsa1, Wsa2,
                                                        idx, parts, outvec);
  bcast_kernel   <<<dim3(512), dim3(256),  0, stream>>>(outvec, (float4*)out);
}

// Round 7
// 248.121 us; speedup vs baseline: 2.4414x; 1.5938x over previous
//
#include <hip/hip_runtime.h>

constexpr int N_ = 4096, C_ = 32, CN_ = 64, M_ = 64;
constexpr int TPB = 512;              // fps block: 8 waves, 2/SIMD
constexpr int RPT = 6, LPT = 2;       // reg / LDS points per thread
constexpr int NREG = RPT * TPB;       // 3072
constexpr int NLDS = LPT * TPB;       // 1024
constexpr int NTPB = 256;             // norms block
constexpr int NCHUNK = N_ / NTPB;     // 16

__device__ __forceinline__ void pkfma(float2& a, float x0, float x1,
                                      float y0, float y1) {
  a.x = fmaf(x0, y0, a.x);
  a.y = fmaf(x1, y1, a.y);
}

// ---------------- kernel 0: per-point z = G·x (f64 accum) + norms + Σx partials ----------------
// blk = (b*3+r)*16 + chunk ; r=0: G=I, r=1: G=Wk^T Wk, r=2: G=Wv^T Wv
__global__ void norms_kernel(const float* __restrict__ ev,
                             const float* __restrict__ Wk,
                             const float* __restrict__ Wv,
                             float* __restrict__ nrm_all,
                             float* __restrict__ zall,
                             float* __restrict__ partials) {
  int blk = blockIdx.x;
  int chunk = blk & (NCHUNK - 1), br = blk >> 4;
  int r = br % 3, b = br / 3;
  int t = threadIdx.x;
  __shared__ float G[C_][C_ + 1];
  const float* W = (r == 1) ? Wk : Wv;
  for (int e = t; e < C_ * C_; e += NTPB) {
    int a = e >> 5, d = e & 31;
    float g;
    if (r == 0) {
      g = (a == d) ? 1.f : 0.f;
    } else {
      double acc = 0.0;
      for (int q = 0; q < CN_; ++q)
        acc += (double)W[q * C_ + a] * (double)W[q * C_ + d];
      g = (float)acc;
    }
    G[a][d] = g;
  }
  __syncthreads();
  int p = chunk * NTPB + t;
  const float4* row = (const float4*)(ev + ((size_t)b * N_ + p) * C_);
  float x[C_];
#pragma unroll
  for (int q = 0; q < C_ / 4; ++q) {
    float4 v = row[q];
    x[q * 4 + 0] = v.x; x[q * 4 + 1] = v.y; x[q * 4 + 2] = v.z; x[q * 4 + 3] = v.w;
  }
  double n = 0.0;
  float z[C_];
#pragma unroll
  for (int a = 0; a < C_; ++a) {
    double ta = 0.0;
#pragma unroll
    for (int d = 0; d < C_; ++d) ta += (double)G[a][d] * (double)x[d];
    z[a] = (float)ta;
    n += ta * (double)x[a];
  }
  nrm_all[(size_t)br * N_ + p] = (float)n;
  float4* zrow = (float4*)(zall + ((size_t)br * N_ + p) * C_);
#pragma unroll
  for (int q = 0; q < C_ / 4; ++q)
    zrow[q] = make_float4(z[q * 4 + 0], z[q * 4 + 1], z[q * 4 + 2], z[q * 4 + 3]);

  if (r == 0) {   // deterministic per-chunk Σx partials (no atomics)
    __shared__ float msum[NTPB / 64][C_];
#pragma unroll
    for (int d = 0; d < C_; ++d) {
      float s = x[d];
#pragma unroll
      for (int off = 32; off; off >>= 1) s += __shfl_xor(s, off);
      if ((t & 63) == 0) msum[t >> 6][d] = s;
    }
    __syncthreads();
    if (t < C_)
      partials[((size_t)b * NCHUNK + chunk) * C_ + t] =
          msum[0][t] + msum[1][t] + msum[2][t] + msum[3][t];
  }
}

// ---------------- kernel 1: FPS — one block per (batch,run), z-metric ----------------
// d(i, sel) = n_i - 2 * z_i · x_sel + n_sel    (G symmetric: x_i·G·c = z_i·c)
__global__ __launch_bounds__(TPB, 2) void fps_kernel(
    const float* __restrict__ ev, const float* __restrict__ nrm_all,
    const float* __restrict__ zall, const float* __restrict__ partials,
    int* __restrict__ idx_ws) {
  const int t = threadIdx.x;
  const int blk = blockIdx.x;          // b*3 + r
  const int b = blk / 3;
  const float* evb = ev + (size_t)b * N_ * C_;
  const float* nrm = nrm_all + (size_t)blk * N_;
  const float4* zb4 = (const float4*)(zall + (size_t)blk * N_ * C_);

  __shared__ float LP[NLDS * C_];      // swizzled z rows of pts 3072..4095 (128 KB)
  __shared__ float cf0[C_];            // barycenter (round 0 only)
  __shared__ float redV[2][TPB / 64];
  __shared__ int   redI[2][TPB / 64];
  __shared__ float redN[2][TPB / 64];  // norm of candidate (carried through reduce)

  float z[RPT][C_], pn[RPT], dmin[RPT];
  float nl[LPT], dminL[LPT];

  // ---- load reg z-points ----
#pragma unroll
  for (int j = 0; j < RPT; ++j) {
    int p = j * TPB + t;
#pragma unroll
    for (int q = 0; q < C_ / 4; ++q) {
      float4 v = zb4[(size_t)p * 8 + q];
      z[j][q * 4 + 0] = v.x; z[j][q * 4 + 1] = v.y;
      z[j][q * 4 + 2] = v.z; z[j][q * 4 + 3] = v.w;
    }
    pn[j] = nrm[p];
    dmin[j] = 1e10f;
  }
  // ---- stage LDS z-points, XOR-quad swizzle ----
#pragma unroll
  for (int i = 0; i < LPT; ++i) {
    int col = i * TPB + t;
    int p = NREG + col;
#pragma unroll
    for (int q = 0; q < C_ / 4; ++q) {
      float4 v = zb4[(size_t)p * 8 + q];
      int off = (col << 5) + ((q ^ (col & 7)) << 2);
      *(float4*)&LP[off] = v;
    }
    nl[i] = nrm[p];
    dminL[i] = 1e10f;
  }
  // ---- barycenter from partials (deterministic) ----
  if (t < C_) {
    float s = 0.f;
#pragma unroll
    for (int c = 0; c < NCHUNK; ++c) s += partials[((size_t)b * NCHUNK + c) * C_ + t];
    cf0[t] = s * (1.f / (float)N_);
  }
  __syncthreads();   // LP + cf0 ready

  auto eval = [&](const float* __restrict__ cf, float curN, bool update,
                  float& bv, int& bi, float& bn) {
    float2 a2[RPT], aL2[LPT];
#pragma unroll
    for (int j = 0; j < RPT; ++j) a2[j] = make_float2(0.f, 0.f);
#pragma unroll
    for (int i = 0; i < LPT; ++i) aL2[i] = make_float2(0.f, 0.f);
    const float4* cf4 = (const float4*)cf;
#pragma unroll
    for (int q = 0; q < C_ / 4; ++q) {
      float4 c = cf4[q];
#pragma unroll
      for (int j = 0; j < RPT; ++j) {
        pkfma(a2[j], z[j][q * 4 + 0], z[j][q * 4 + 1], c.x, c.y);
        pkfma(a2[j], z[j][q * 4 + 2], z[j][q * 4 + 3], c.z, c.w);
      }
#pragma unroll
      for (int i = 0; i < LPT; ++i) {
        int col = i * TPB + t;
        int off = (col << 5) + ((q ^ (col & 7)) << 2);
        float4 l = *(const float4*)&LP[off];
        pkfma(aL2[i], l.x, l.y, c.x, c.y);
        pkfma(aL2[i], l.z, l.w, c.z, c.w);
      }
    }
    bv = -3e38f; bi = 0x7fffffff; bn = 0.f;
#pragma unroll
    for (int j = 0; j < RPT; ++j) {
      float acc = a2[j].x + a2[j].y;
      float d = fmaf(-2.f, acc, pn[j]) + curN;
      float v;
      if (update) { dmin[j] = fminf(dmin[j], d); v = dmin[j]; }
      else v = d;
      int p = j * TPB + t;
      if (v > bv) { bv = v; bi = p; bn = pn[j]; }
    }
#pragma unroll
    for (int i = 0; i < LPT; ++i) {
      float acc = aL2[i].x + aL2[i].y;
      float d = fmaf(-2.f, acc, nl[i]) + curN;
      float v;
      if (update) { dminL[i] = fminf(dminL[i], d); v = dminL[i]; }
      else v = d;
      int p = NREG + i * TPB + t;
      if (v > bv) { bv = v; bi = p; bn = nl[i]; }
    }
    // wave argmax, lowest-index tie-break (jnp.argmax first-max semantics)
#pragma unroll
    for (int off = 1; off < 64; off <<= 1) {
      float ov = __shfl_xor(bv, off);
      int   oi = __shfl_xor(bi, off);
      float on = __shfl_xor(bn, off);
      if (ov > bv || (ov == bv && oi < bi)) { bv = ov; bi = oi; bn = on; }
    }
  };

  // ---- round 0: barycenter (curN shift irrelevant for argmax; no dmin update) ----
  {
    float bv, bn; int bi;
    eval(cf0, 0.f, false, bv, bi, bn);
    if ((t & 63) == 0) { redV[0][t >> 6] = bv; redI[0][t >> 6] = bi; redN[0][t >> 6] = bn; }
  }
  __syncthreads();

  // ---- main loop: 1 barrier per iteration, double-buffered reduce slots ----
  for (int it = 0; it < M_; ++it) {
    int rb = it & 1;
    // every thread redundantly scans the 8 wave entries -> identical jsel
    float fv = redV[rb][0]; int fi = redI[rb][0]; float fn = redN[rb][0];
#pragma unroll
    for (int w = 1; w < TPB / 64; ++w) {
      float wv = redV[rb][w]; int wi = redI[rb][w]; float wn = redN[rb][w];
      if (wv > fv || (wv == fv && wi < fi)) { fv = wv; fi = wi; fn = wn; }
    }
    int jsel = fi;
    if (t == 0) idx_ws[blk * M_ + it] = jsel;
    // owner kills its dmin slot (never re-select)
    if (jsel < NREG) {
      int j = jsel >> 9, tt = jsel & (TPB - 1);
      if (t == tt) dmin[j] = -3e38f;
    } else {
      int col = jsel - NREG;
      int i = col >> 9, tt = col & (TPB - 1);
      if (t == tt) dminL[i] = -3e38f;
    }
    if (it == M_ - 1) break;
    // curN carried through the reduce (fn) -> no nrm[jsel] load.
    // jsel provably wave-uniform -> scalar (s_load) cf fetch.
    int jsu = __builtin_amdgcn_readfirstlane(jsel);
    const float* cf = evb + (size_t)jsu * C_;
    float bv, bn; int bi;
    eval(cf, fn, true, bv, bi, bn);
    if ((t & 63) == 0) { redV[rb ^ 1][t >> 6] = bv; redI[rb ^ 1][t >> 6] = bi; redN[rb ^ 1][t >> 6] = bn; }
    __syncthreads();
  }
}

// ---------------- kernel 2: finalize (256 threads per batch) ----------------
// fps() returns selections in ASCENDING ORIGINAL-INDEX order (masked_select);
// rank-sort each run's indices before zipping along m (pairing matters).
// PRJ[0]=pe (ev-run pts @ Wpe), PRJ[1]=km (k-run pts @ Wk), PRJ[2]=vm (v-run @ Wv).
__global__ void finalize_kernel(
    const float* __restrict__ ev, const float* __restrict__ Wk,
    const float* __restrict__ Wv, const float* __restrict__ Wpe,
    const float* __restrict__ Wsa1, const float* __restrict__ Wsa2,
    const int* __restrict__ idx_ws, const float* __restrict__ partials,
    float* __restrict__ outvec_ws) {
  const int b = blockIdx.x;
  const int t = threadIdx.x;           // 256 threads
  const float* evb = ev + (size_t)b * N_ * C_;

  __shared__ int   lidx[3][M_], sidx[3][M_];
  __shared__ float PRJ[3][M_][CN_ + 1];    // padded: conflict-free column reads
  __shared__ float sumx[C_];

  if (t < 192) {
    int r = t >> 6, mm = t & 63;
    lidx[r][mm] = idx_ws[(b * 3 + r) * M_ + mm];
  }
  if (t < C_) {
    float s = 0.f;
#pragma unroll
    for (int c = 0; c < NCHUNK; ++c) s += partials[((size_t)b * NCHUNK + c) * C_ + t];
    sumx[t] = s;
  }
  __syncthreads();
  if (t < 192) {       // parallel rank-sort: 3 runs × 64 slots
    int r = t >> 6, mm = t & 63;
    int my = lidx[r][mm];
    int rank = 0;
#pragma unroll
    for (int j = 0; j < M_; ++j)
      rank += (lidx[r][j] < my) || (lidx[r][j] == my && j < mm);
    sidx[r][rank] = my;
  }
  __syncthreads();

  // ---- projections: thread (m = t>>2, qq = t&3) computes 16 cn per matrix ----
  {
    int m = t >> 2, qq = t & 3;
    const float* Ws[3] = {Wpe, Wk, Wv};
#pragma unroll
    for (int r = 0; r < 3; ++r) {
      int pi = sidx[r][m];
      const float4* xr = (const float4*)(evb + (size_t)pi * C_);
      float x[C_];
#pragma unroll
      for (int q = 0; q < C_ / 4; ++q) {
        float4 v = xr[q];
        x[q * 4 + 0] = v.x; x[q * 4 + 1] = v.y; x[q * 4 + 2] = v.z; x[q * 4 + 3] = v.w;
      }
#pragma unroll 4
      for (int i = 0; i < 16; ++i) {
        int cn = qq * 16 + i;
        const float4* wr = (const float4*)(Ws[r] + cn * C_);
        float a = 0.f;
#pragma unroll
        for (int q = 0; q < C_ / 4; ++q) {
          float4 w = wr[q];
          a = fmaf(x[q * 4 + 0], w.x, a);
          a = fmaf(x[q * 4 + 1], w.y, a);
          a = fmaf(x[q * 4 + 2], w.z, a);
          a = fmaf(x[q * 4 + 3], w.w, a);
        }
        PRJ[r][m][cn] = a;
      }
    }
  }
  __syncthreads();

  // ---- tail: wave 0 only, LDS + shfl, no barriers ----
  if (t < 64) {
    // Pl[cn=t] = (Σ_n ev) @ Wpe^T
    float Plt = 0.f;
    {
      const float4* wr = (const float4*)(Wpe + t * C_);
#pragma unroll
      for (int q = 0; q < C_ / 4; ++q) {
        float4 w = wr[q];
        float4 s4 = *(const float4*)&sumx[q * 4];
        Plt = fmaf(s4.x, w.x, fmaf(s4.y, w.y, fmaf(s4.z, w.z, fmaf(s4.w, w.w, Plt))));
      }
    }
    // logits: lane m = t
    float cm = 0.f;
#pragma unroll 8
    for (int cn = 0; cn < CN_; ++cn)
      cm = fmaf(PRJ[1][t][cn] + PRJ[0][t][cn], Wsa1[cn], cm);
    float lg = -cm;
    float mx = lg;
#pragma unroll
    for (int off = 32; off; off >>= 1) mx = fmaxf(mx, __shfl_xor(mx, off));
    float e = expf(lg - mx);
    float ssum = e;
#pragma unroll
    for (int off = 32; off; off >>= 1) ssum += __shfl_xor(ssum, off);
    float s = e / ssum;
    // tvec[cn=t] = Σ_m s_m * (N*vm[m][cn] + Pl[cn] - N*pe[m][cn])
    float acc = 0.f;
    for (int mm = 0; mm < M_; ++mm) {
      float sm = __shfl(s, mm);
      acc = fmaf(sm, fmaf((float)N_, PRJ[2][mm][t], Plt) - (float)N_ * PRJ[0][mm][t], acc);
    }
    // out[c] = Σ_cn tvec[cn] * Wsa2[c][cn]  (transpose via shfl)
    float o = 0.f;
    for (int cn = 0; cn < CN_; ++cn) {
      float tv = __shfl(acc, cn);
      if (t < C_) o = fmaf(tv, Wsa2[t * CN_ + cn], o);
    }
    if (t < C_) outvec_ws[b * C_ + t] = o;
  }
}

// ---------------- kernel 3: broadcast out[b][n][:] = outvec[b][:] ----------------
__global__ void bcast_kernel(const float* __restrict__ outvec_ws,
                             float4* __restrict__ out) {
  int i = blockIdx.x * 256 + threadIdx.x;   // < 4*4096*8
  int b = i >> 15;
  int j = i & 7;
  const float4* ov = (const float4*)outvec_ws;
  out[i] = ov[b * 8 + j];
}

extern "C" void kernel_launch(void* const* d_in, const int* in_sizes, int n_in,
                              void* d_out, int out_size, void* d_ws, size_t ws_size,
                              hipStream_t stream) {
  const float* ev   = (const float*)d_in[0];
  // d_in[1] = W_qs: provably unused (a_n cancels in softmax over m)
  const float* Wk   = (const float*)d_in[2];
  const float* Wv   = (const float*)d_in[3];
  const float* Wpe  = (const float*)d_in[4];
  const float* Wsa1 = (const float*)d_in[5];
  const float* Wsa2 = (const float*)d_in[6];
  float* out = (float*)d_out;

  char* ws = (char*)d_ws;
  int*   idx    = (int*)ws;                     // 12*64*4        = 3072 B
  float* parts  = (float*)(ws + 3072);          // 4*16*32*4      = 8192 B
  float* outvec = (float*)(ws + 11264);         // 4*32*4         = 512 B
  float* nrm    = (float*)(ws + 11776);         // 12*4096*4      = 196608 B
  float* zall   = (float*)(ws + 208384);        // 12*4096*32*4   = 6291456 B

  norms_kernel   <<<dim3(192), dim3(NTPB), 0, stream>>>(ev, Wk, Wv, nrm, zall, parts);
  fps_kernel     <<<dim3(12),  dim3(TPB),  0, stream>>>(ev, nrm, zall, parts, idx);
  finalize_kernel<<<dim3(4),   dim3(256),  0, stream>>>(ev, Wk, Wv, Wpe, Wsa1, Wsa2,
                                                        idx, parts, outvec);
  bcast_kernel   <<<dim3(512), dim3(256),  0, stream>>>(outvec, (float4*)out);
}

// Round 8
// 237.552 us; speedup vs baseline: 2.5500x; 1.0445x over previous
//
#include <hip/hip_runtime.h>

constexpr int N_ = 4096, C_ = 32, CN_ = 64, M_ = 64;
constexpr int TPB = 1024;             // fps block: 16 waves, 4/SIMD
constexpr int RPT = 3, LPT = 1;       // reg / LDS points per thread
constexpr int NREG = RPT * TPB;       // 3072
constexpr int NLDS = N_ - NREG;       // 1024
constexpr int NWAVES = TPB / 64;      // 16
constexpr int NTPB = 256;             // norms block
constexpr int NCHUNK = N_ / NTPB;     // 16

__device__ __forceinline__ void pkfma(float2& a, float x0, float x1,
                                      float y0, float y1) {
  a.x = fmaf(x0, y0, a.x);
  a.y = fmaf(x1, y1, a.y);
}

__device__ __forceinline__ unsigned long long shfl_xor_u64(unsigned long long v, int m) {
  unsigned lo = __shfl_xor((unsigned)v, m);
  unsigned hi = __shfl_xor((unsigned)(v >> 32), m);
  return ((unsigned long long)hi << 32) | lo;
}

// monotone f32 -> u32 map (total order preserved incl. negatives)
__device__ __forceinline__ unsigned fmap(float v) {
  unsigned u = __float_as_uint(v);
  u ^= (unsigned)((int)u >> 31) | 0x80000000u;
  return u;
}

// ---------------- kernel 0: per-point z = G·x (f64 accum) + norms + Σx partials ----------------
// blk = (b*3+r)*16 + chunk ; r=0: G=I, r=1: G=Wk^T Wk, r=2: G=Wv^T Wv
__global__ void norms_kernel(const float* __restrict__ ev,
                             const float* __restrict__ Wk,
                             const float* __restrict__ Wv,
                             float* __restrict__ nrm_all,
                             float* __restrict__ zall,
                             float* __restrict__ partials) {
  int blk = blockIdx.x;
  int chunk = blk & (NCHUNK - 1), br = blk >> 4;
  int r = br % 3, b = br / 3;
  int t = threadIdx.x;
  __shared__ float G[C_][C_ + 1];
  const float* W = (r == 1) ? Wk : Wv;
  for (int e = t; e < C_ * C_; e += NTPB) {
    int a = e >> 5, d = e & 31;
    float g;
    if (r == 0) {
      g = (a == d) ? 1.f : 0.f;
    } else {
      double acc = 0.0;
      for (int q = 0; q < CN_; ++q)
        acc += (double)W[q * C_ + a] * (double)W[q * C_ + d];
      g = (float)acc;
    }
    G[a][d] = g;
  }
  __syncthreads();
  int p = chunk * NTPB + t;
  const float4* row = (const float4*)(ev + ((size_t)b * N_ + p) * C_);
  float x[C_];
#pragma unroll
  for (int q = 0; q < C_ / 4; ++q) {
    float4 v = row[q];
    x[q * 4 + 0] = v.x; x[q * 4 + 1] = v.y; x[q * 4 + 2] = v.z; x[q * 4 + 3] = v.w;
  }
  double n = 0.0;
  float z[C_];
#pragma unroll
  for (int a = 0; a < C_; ++a) {
    double ta = 0.0;
#pragma unroll
    for (int d = 0; d < C_; ++d) ta += (double)G[a][d] * (double)x[d];
    z[a] = (float)ta;
    n += ta * (double)x[a];
  }
  nrm_all[(size_t)br * N_ + p] = (float)n;
  float4* zrow = (float4*)(zall + ((size_t)br * N_ + p) * C_);
#pragma unroll
  for (int q = 0; q < C_ / 4; ++q)
    zrow[q] = make_float4(z[q * 4 + 0], z[q * 4 + 1], z[q * 4 + 2], z[q * 4 + 3]);

  if (r == 0) {   // deterministic per-chunk Σx partials (no atomics)
    __shared__ float msum[NTPB / 64][C_];
#pragma unroll
    for (int d = 0; d < C_; ++d) {
      float s = x[d];
#pragma unroll
      for (int off = 32; off; off >>= 1) s += __shfl_xor(s, off);
      if ((t & 63) == 0) msum[t >> 6][d] = s;
    }
    __syncthreads();
    if (t < C_)
      partials[((size_t)b * NCHUNK + chunk) * C_ + t] =
          msum[0][t] + msum[1][t] + msum[2][t] + msum[3][t];
  }
}

// ---------------- kernel 1: FPS — one block per (batch,run), z-metric ----------------
// d(i, sel) = n_i - 2 * z_i · x_sel + n_sel    (G symmetric: x_i·G·c = z_i·c)
__global__ __launch_bounds__(TPB, 4) void fps_kernel(
    const float* __restrict__ ev, const float* __restrict__ nrm_all,
    const float* __restrict__ zall, const float* __restrict__ partials,
    int* __restrict__ idx_ws) {
  const int t = threadIdx.x;
  const int blk = blockIdx.x;          // b*3 + r
  const int b = blk / 3;
  const float* evb = ev + (size_t)b * N_ * C_;
  const float* nrm = nrm_all + (size_t)blk * N_;
  const float4* zb4 = (const float4*)(zall + (size_t)blk * N_ * C_);

  __shared__ float LP[C_ / 4][NLDS][4];   // [q][col][4] — conflict-free b128 (128 KB)
  __shared__ float cf0[C_];               // barycenter (round 0 only)
  __shared__ unsigned long long redK[2][NWAVES];

  float z[RPT][C_], pn[RPT], dmin[RPT];
  float nl, dminL;

  // ---- load reg z-points ----
#pragma unroll
  for (int j = 0; j < RPT; ++j) {
    int p = j * TPB + t;
#pragma unroll
    for (int q = 0; q < C_ / 4; ++q) {
      float4 v = zb4[(size_t)p * 8 + q];
      z[j][q * 4 + 0] = v.x; z[j][q * 4 + 1] = v.y;
      z[j][q * 4 + 2] = v.z; z[j][q * 4 + 3] = v.w;
    }
    pn[j] = nrm[p];
    dmin[j] = 1e10f;
  }
  // ---- stage LDS z-point (1 per thread), [q][col] layout ----
  {
    int p = NREG + t;
#pragma unroll
    for (int q = 0; q < C_ / 4; ++q) {
      float4 v = zb4[(size_t)p * 8 + q];
      *(float4*)&LP[q][t][0] = v;
    }
    nl = nrm[p];
    dminL = 1e10f;
  }
  // ---- barycenter from partials (deterministic) ----
  if (t < C_) {
    float s = 0.f;
#pragma unroll
    for (int c = 0; c < NCHUNK; ++c) s += partials[((size_t)b * NCHUNK + c) * C_ + t];
    cf0[t] = s * (1.f / (float)N_);
  }
  __syncthreads();   // LP + cf0 ready

  // returns wave-reduced packed key: (fmap(best_v) << 12) | (4095 - best_idx)
  auto eval = [&](const float* __restrict__ cf, float curN,
                  bool update) -> unsigned long long {
    float2 a2[RPT], aL;
#pragma unroll
    for (int j = 0; j < RPT; ++j) a2[j] = make_float2(0.f, 0.f);
    aL = make_float2(0.f, 0.f);
    const float4* cf4 = (const float4*)cf;
#pragma unroll
    for (int q = 0; q < C_ / 4; ++q) {
      float4 c = cf4[q];
#pragma unroll
      for (int j = 0; j < RPT; ++j) {
        pkfma(a2[j], z[j][q * 4 + 0], z[j][q * 4 + 1], c.x, c.y);
        pkfma(a2[j], z[j][q * 4 + 2], z[j][q * 4 + 3], c.z, c.w);
      }
      float4 l = *(const float4*)&LP[q][t][0];
      pkfma(aL, l.x, l.y, c.x, c.y);
      pkfma(aL, l.z, l.w, c.z, c.w);
    }
    float bv = -3e38f; int bi = 0;
#pragma unroll
    for (int j = 0; j < RPT; ++j) {
      float acc = a2[j].x + a2[j].y;
      float d = fmaf(-2.f, acc, pn[j]) + curN;
      float v;
      if (update) { dmin[j] = fminf(dmin[j], d); v = dmin[j]; }
      else v = d;
      if (v > bv) { bv = v; bi = j * TPB + t; }   // strict > keeps lowest index
    }
    {
      float acc = aL.x + aL.y;
      float d = fmaf(-2.f, acc, nl) + curN;
      float v;
      if (update) { dminL = fminf(dminL, d); v = dminL; }
      else v = d;
      if (v > bv) { bv = v; bi = NREG + t; }
    }
    unsigned long long k =
        ((unsigned long long)fmap(bv) << 12) | (unsigned)(4095 - bi);
#pragma unroll
    for (int off = 1; off < 64; off <<= 1) {
      unsigned long long ko = shfl_xor_u64(k, off);
      if (ko > k) k = ko;
    }
    return k;
  };

  // ---- round 0: barycenter (additive shift irrelevant for argmax; no dmin update) ----
  {
    unsigned long long k = eval(cf0, 0.f, false);
    if ((t & 63) == 0) redK[0][t >> 6] = k;
  }
  __syncthreads();

  // ---- main loop: 1 barrier per iteration, double-buffered reduce slots ----
  for (int it = 0; it < M_; ++it) {
    int rb = it & 1;
    unsigned long long k = redK[rb][0];
#pragma unroll
    for (int w = 1; w < NWAVES; ++w) {
      unsigned long long kw = redK[rb][w];
      if (kw > k) k = kw;
    }
    int jsel = 4095 - (int)(k & 4095ull);
    if (t == 0) idx_ws[blk * M_ + it] = jsel;
    // owner kills its dmin slot (never re-select) — static indices only
    if (jsel < NREG) {
      if ((jsel & (TPB - 1)) == t) {
        int j = jsel >> 10;
        if (j == 0) dmin[0] = -3e38f;
        else if (j == 1) dmin[1] = -3e38f;
        else dmin[2] = -3e38f;
      }
    } else {
      if (jsel - NREG == t) dminL = -3e38f;
    }
    if (it == M_ - 1) break;
    // uniform index -> scalar loads of centroid features and its norm (overlap)
    int jsu = __builtin_amdgcn_readfirstlane(jsel);
    float curN = nrm[jsu];
    const float* cf = evb + (size_t)jsu * C_;
    unsigned long long kk = eval(cf, curN, true);
    if ((t & 63) == 0) redK[rb ^ 1][t >> 6] = kk;
    __syncthreads();
  }
}

// ---------------- kernel 2: finalize (256 threads per batch) ----------------
// fps() returns selections in ASCENDING ORIGINAL-INDEX order (masked_select);
// rank-sort each run's indices before zipping along m (pairing matters).
// PRJ[0]=pe (ev-run pts @ Wpe), PRJ[1]=km (k-run pts @ Wk), PRJ[2]=vm (v-run @ Wv).
__global__ void finalize_kernel(
    const float* __restrict__ ev, const float* __restrict__ Wk,
    const float* __restrict__ Wv, const float* __restrict__ Wpe,
    const float* __restrict__ Wsa1, const float* __restrict__ Wsa2,
    const int* __restrict__ idx_ws, const float* __restrict__ partials,
    float* __restrict__ outvec_ws) {
  const int b = blockIdx.x;
  const int t = threadIdx.x;           // 256 threads = 4 waves
  const float* evb = ev + (size_t)b * N_ * C_;

  __shared__ float Wl[3][CN_][C_];        // 24 KB: Wpe, Wk, Wv
  __shared__ float W1l[CN_];
  __shared__ float W2l[C_][CN_ + 1];      // padded: conflict-free per-lane rows
  __shared__ int   lidx[3][M_], sidx[3][M_];
  __shared__ float XP[3][M_][C_];         // 24 KB selected rows
  __shared__ float PRJ[3][M_][CN_ + 1];   // padded
  __shared__ float sumx[C_], Pl[CN_], sl[M_], TP[4][CN_];

  // ---- stage weights ----
  {
    const float* Ws[3] = {Wpe, Wk, Wv};
#pragma unroll
    for (int r = 0; r < 3; ++r)
      for (int i = t; i < CN_ * C_ / 4; i += 256)
        ((float4*)&Wl[r][0][0])[i] = ((const float4*)Ws[r])[i];
    if (t < CN_) W1l[t] = Wsa1[t];
    for (int i = t; i < C_ * CN_; i += 256)
      W2l[i >> 6][i & 63] = Wsa2[i];      // scalar (padded dest not f4-aligned)
  }
  if (t < 192) {
    int r = t >> 6, mm = t & 63;
    lidx[r][mm] = idx_ws[(b * 3 + r) * M_ + mm];
  }
  if (t < C_) {
    float s = 0.f;
#pragma unroll
    for (int c = 0; c < NCHUNK; ++c) s += partials[((size_t)b * NCHUNK + c) * C_ + t];
    sumx[t] = s;
  }
  __syncthreads();
  if (t < 192) {       // parallel rank-sort: 3 runs × 64 slots
    int r = t >> 6, mm = t & 63;
    int my = lidx[r][mm];
    int rank = 0;
#pragma unroll
    for (int j = 0; j < M_; ++j)
      rank += (lidx[r][j] < my) || (lidx[r][j] == my && j < mm);
    sidx[r][rank] = my;
  }
  __syncthreads();
  // ---- stage selected rows: 192 rows × 8 quads ----
  for (int g = t; g < 3 * M_ * 8; g += 256) {
    int row = g >> 3, q = g & 7;
    int r = row >> 6, m = row & 63;
    int pi = sidx[r][m];
    *(float4*)&XP[r][m][q * 4] = ((const float4*)(evb + (size_t)pi * C_))[q];
  }
  __syncthreads();
  // ---- projections: wave r handles run r (lane = cn, W row in regs, x broadcast) ----
  {
    int w = t >> 6, cn = t & 63;
    if (w < 3) {
      float wr[C_];
#pragma unroll
      for (int q = 0; q < C_ / 4; ++q) {
        float4 v = *(const float4*)&Wl[w][cn][q * 4];
        wr[q * 4 + 0] = v.x; wr[q * 4 + 1] = v.y;
        wr[q * 4 + 2] = v.z; wr[q * 4 + 3] = v.w;
      }
      for (int m = 0; m < M_; ++m) {
        float2 a = make_float2(0.f, 0.f);
#pragma unroll
        for (int q = 0; q < C_ / 4; ++q) {
          float4 x = *(const float4*)&XP[w][m][q * 4];   // wave-broadcast read
          pkfma(a, x.x, x.y, wr[q * 4 + 0], wr[q * 4 + 1]);
          pkfma(a, x.z, x.w, wr[q * 4 + 2], wr[q * 4 + 3]);
        }
        PRJ[w][m][cn] = a.x + a.y;
      }
    } else {
      // Pl[cn] = (Σ_n ev) @ Wpe^T
      float a = 0.f;
#pragma unroll
      for (int c = 0; c < C_; ++c) a = fmaf(sumx[c], Wl[0][cn][c], a);
      Pl[cn] = a;
    }
  }
  __syncthreads();
  // ---- logits + softmax: wave 0, lane m ----
  if (t < 64) {
    float cm = 0.f;
#pragma unroll 8
    for (int cn = 0; cn < CN_; ++cn)
      cm = fmaf(PRJ[1][t][cn] + PRJ[0][t][cn], W1l[cn], cm);
    float lg = -cm;
    float mx = lg;
#pragma unroll
    for (int off = 32; off; off >>= 1) mx = fmaxf(mx, __shfl_xor(mx, off));
    float e = expf(lg - mx);
    float ssum = e;
#pragma unroll
    for (int off = 32; off; off >>= 1) ssum += __shfl_xor(ssum, off);
    sl[t] = e / ssum;
  }
  __syncthreads();
  // ---- tvec partials: thread (cn = t&63, quarter h = t>>6) ----
  {
    int cn = t & 63, h = t >> 6;
    float a = 0.f;
#pragma unroll
    for (int i = 0; i < 16; ++i) {
      int mm = h * 16 + i;
      a = fmaf(sl[mm],
               fmaf((float)N_, PRJ[2][mm][cn], Pl[cn]) - (float)N_ * PRJ[0][mm][cn],
               a);
    }
    TP[h][cn] = a;
  }
  __syncthreads();
  if (t < C_) {
    float o = 0.f;
#pragma unroll 8
    for (int cn = 0; cn < CN_; ++cn) {
      float tv = TP[0][cn] + TP[1][cn] + TP[2][cn] + TP[3][cn];
      o = fmaf(tv, W2l[t][cn], o);
    }
    outvec_ws[b * C_ + t] = o;
  }
}

// ---------------- kernel 3: broadcast out[b][n][:] = outvec[b][:] ----------------
__global__ void bcast_kernel(const float* __restrict__ outvec_ws,
                             float4* __restrict__ out) {
  int i = blockIdx.x * 256 + threadIdx.x;   // < 4*4096*8
  int b = i >> 15;
  int j = i & 7;
  const float4* ov = (const float4*)outvec_ws;
  out[i] = ov[b * 8 + j];
}

extern "C" void kernel_launch(void* const* d_in, const int* in_sizes, int n_in,
                              void* d_out, int out_size, void* d_ws, size_t ws_size,
                              hipStream_t stream) {
  const float* ev   = (const float*)d_in[0];
  // d_in[1] = W_qs: provably unused (a_n cancels in softmax over m)
  const float* Wk   = (const float*)d_in[2];
  const float* Wv   = (const float*)d_in[3];
  const float* Wpe  = (const float*)d_in[4];
  const float* Wsa1 = (const float*)d_in[5];
  const float* Wsa2 = (const float*)d_in[6];
  float* out = (float*)d_out;

  char* ws = (char*)d_ws;
  int*   idx    = (int*)ws;                     // 12*64*4        = 3072 B
  float* parts  = (float*)(ws + 3072);          // 4*16*32*4      = 8192 B
  float* outvec = (float*)(ws + 11264);         // 4*32*4         = 512 B
  float* nrm    = (float*)(ws + 11776);         // 12*4096*4      = 196608 B
  float* zall   = (float*)(ws + 208384);        // 12*4096*32*4   = 6291456 B

  norms_kernel   <<<dim3(192), dim3(NTPB), 0, stream>>>(ev, Wk, Wv, nrm, zall, parts);
  fps_kernel     <<<dim3(12),  dim3(TPB),  0, stream>>>(ev, nrm, zall, parts, idx);
  finalize_kernel<<<dim3(4),   dim3(256),  0, stream>>>(ev, Wk, Wv, Wpe, Wsa1, Wsa2,
                                                        idx, parts, outvec);
  bcast_kernel   <<<dim3(512), dim3(256),  0, stream>>>(outvec, (float4*)out);
}

// Round 9
// 193.712 us; speedup vs baseline: 3.1271x; 1.2263x over previous
//
#include <hip/hip_runtime.h>

constexpr int N_ = 4096, C_ = 32, CN_ = 64, M_ = 64;
constexpr int TPB = 1024;             // fps block: 16 waves, 4/SIMD
constexpr int RPT = 3, LPT = 1;       // reg / LDS points per thread
constexpr int NREG = RPT * TPB;       // 3072
constexpr int NLDS = N_ - NREG;       // 1024
constexpr int NWAVES = TPB / 64;      // 16
constexpr int NTPB = 256;             // norms block
constexpr int NCHUNK = N_ / NTPB;     // 16

__device__ __forceinline__ void pkfma(float2& a, float x0, float x1,
                                      float y0, float y1) {
  a.x = fmaf(x0, y0, a.x);
  a.y = fmaf(x1, y1, a.y);
}

__device__ __forceinline__ unsigned long long shfl_xor_u64(unsigned long long v, int m) {
  unsigned lo = __shfl_xor((unsigned)v, m);
  unsigned hi = __shfl_xor((unsigned)(v >> 32), m);
  return ((unsigned long long)hi << 32) | lo;
}

// monotone f32 -> u32 map (total order preserved incl. negatives)
__device__ __forceinline__ unsigned fmap(float v) {
  unsigned u = __float_as_uint(v);
  u ^= (unsigned)((int)u >> 31) | 0x80000000u;
  return u;
}

// force a wave-uniform float into an SGPR
__device__ __forceinline__ float rfl(float v) {
  return __uint_as_float(__builtin_amdgcn_readfirstlane(__float_as_uint(v)));
}

// ---------------- kernel 0: per-point z = G·x (f64 accum) + norms + Σx partials ----------------
// blk = (b*3+r)*16 + chunk ; r=0: G=I, r=1: G=Wk^T Wk, r=2: G=Wv^T Wv
__global__ __launch_bounds__(NTPB, 1) void norms_kernel(
    const float* __restrict__ ev, const float* __restrict__ Wk,
    const float* __restrict__ Wv, float* __restrict__ nrm_all,
    float* __restrict__ zall, float* __restrict__ partials) {
  int blk = blockIdx.x;
  int chunk = blk & (NCHUNK - 1), br = blk >> 4;
  int r = br % 3, b = br / 3;
  int t = threadIdx.x;
  __shared__ float G[C_][C_ + 1];
  const float* W = (r == 1) ? Wk : Wv;
  for (int e = t; e < C_ * C_; e += NTPB) {
    int a = e >> 5, d = e & 31;
    float g;
    if (r == 0) {
      g = (a == d) ? 1.f : 0.f;
    } else {
      double acc = 0.0;
      for (int q = 0; q < CN_; ++q)
        acc += (double)W[q * C_ + a] * (double)W[q * C_ + d];
      g = (float)acc;
    }
    G[a][d] = g;
  }
  __syncthreads();
  int p = chunk * NTPB + t;
  const float4* row = (const float4*)(ev + ((size_t)b * N_ + p) * C_);
  float x[C_];
#pragma unroll
  for (int q = 0; q < C_ / 4; ++q) {
    float4 v = row[q];
    x[q * 4 + 0] = v.x; x[q * 4 + 1] = v.y; x[q * 4 + 2] = v.z; x[q * 4 + 3] = v.w;
  }
  double n = 0.0;
  float z[C_];
#pragma unroll
  for (int a = 0; a < C_; ++a) {
    double ta = 0.0;
#pragma unroll
    for (int d = 0; d < C_; ++d) ta += (double)G[a][d] * (double)x[d];
    z[a] = (float)ta;
    n += ta * (double)x[a];
  }
  nrm_all[(size_t)br * N_ + p] = (float)n;
  float4* zrow = (float4*)(zall + ((size_t)br * N_ + p) * C_);
#pragma unroll
  for (int q = 0; q < C_ / 4; ++q)
    zrow[q] = make_float4(z[q * 4 + 0], z[q * 4 + 1], z[q * 4 + 2], z[q * 4 + 3]);

  if (r == 0) {   // deterministic per-chunk Σx partials (no atomics)
    __shared__ float msum[NTPB / 64][C_];
#pragma unroll
    for (int d = 0; d < C_; ++d) {
      float s = x[d];
#pragma unroll
      for (int off = 32; off; off >>= 1) s += __shfl_xor(s, off);
      if ((t & 63) == 0) msum[t >> 6][d] = s;
    }
    __syncthreads();
    if (t < C_)
      partials[((size_t)b * NCHUNK + chunk) * C_ + t] =
          msum[0][t] + msum[1][t] + msum[2][t] + msum[3][t];
  }
}

// ---------------- kernel 1: FPS — one block per (batch,run), z-metric ----------------
// d(i, sel) = n_i - 2 * z_i · x_sel + n_sel    (G symmetric: x_i·G·c = z_i·c)
// __launch_bounds__(1024, 1): flat-wg=1024 forces 16 co-resident waves ->
// VGPR budget exactly 128 (round-8's (1024,4) capped it at 64 -> 579KB spill).
__global__ __launch_bounds__(TPB, 1) void fps_kernel(
    const float* __restrict__ ev, const float* __restrict__ nrm_all,
    const float* __restrict__ zall, const float* __restrict__ partials,
    int* __restrict__ idx_ws) {
  const int t = threadIdx.x;
  const int blk = blockIdx.x;          // b*3 + r
  const int b = blk / 3;
  const float* evb = ev + (size_t)b * N_ * C_;
  const float* nrm = nrm_all + (size_t)blk * N_;
  const float4* zb4 = (const float4*)(zall + (size_t)blk * N_ * C_);

  __shared__ float LP[C_ / 4][NLDS][4];   // [q][col][4] — conflict-free b128 (128 KB)
  __shared__ float cf0[C_];               // barycenter (round 0 only)
  __shared__ unsigned long long redK[2][NWAVES];

  float z[RPT][C_], pn[RPT], dmin[RPT];
  float nl, dminL;

  // ---- load reg z-points ----
#pragma unroll
  for (int j = 0; j < RPT; ++j) {
    int p = j * TPB + t;
#pragma unroll
    for (int q = 0; q < C_ / 4; ++q) {
      float4 v = zb4[(size_t)p * 8 + q];
      z[j][q * 4 + 0] = v.x; z[j][q * 4 + 1] = v.y;
      z[j][q * 4 + 2] = v.z; z[j][q * 4 + 3] = v.w;
    }
    pn[j] = nrm[p];
    dmin[j] = 1e10f;
  }
  // ---- stage LDS z-point (1 per thread), [q][col] layout ----
  {
    int p = NREG + t;
#pragma unroll
    for (int q = 0; q < C_ / 4; ++q) {
      float4 v = zb4[(size_t)p * 8 + q];
      *(float4*)&LP[q][t][0] = v;
    }
    nl = nrm[p];
    dminL = 1e10f;
  }
  // ---- barycenter from partials (deterministic) ----
  if (t < C_) {
    float s = 0.f;
#pragma unroll
    for (int c = 0; c < NCHUNK; ++c) s += partials[((size_t)b * NCHUNK + c) * C_ + t];
    cf0[t] = s * (1.f / (float)N_);
  }
  __syncthreads();   // LP + cf0 ready

  // cs[] is wave-uniform (SGPR-resident): FMAs take 1 SGPR operand, no VGPR cost.
  // returns wave-reduced packed key: (fmap(best_v) << 12) | (4095 - best_idx)
  auto eval = [&](const float (&cs)[C_], float curN,
                  bool update) -> unsigned long long {
    float2 a2[RPT], aL;
#pragma unroll
    for (int j = 0; j < RPT; ++j) a2[j] = make_float2(0.f, 0.f);
    aL = make_float2(0.f, 0.f);
#pragma unroll
    for (int q = 0; q < C_ / 4; ++q) {
#pragma unroll
      for (int j = 0; j < RPT; ++j) {
        pkfma(a2[j], z[j][q * 4 + 0], z[j][q * 4 + 1], cs[q * 4 + 0], cs[q * 4 + 1]);
        pkfma(a2[j], z[j][q * 4 + 2], z[j][q * 4 + 3], cs[q * 4 + 2], cs[q * 4 + 3]);
      }
      float4 l = *(const float4*)&LP[q][t][0];
      pkfma(aL, l.x, l.y, cs[q * 4 + 0], cs[q * 4 + 1]);
      pkfma(aL, l.z, l.w, cs[q * 4 + 2], cs[q * 4 + 3]);
    }
    float bv = -3e38f; int bi = 0;
#pragma unroll
    for (int j = 0; j < RPT; ++j) {
      float acc = a2[j].x + a2[j].y;
      float d = fmaf(-2.f, acc, pn[j]) + curN;
      float v;
      if (update) { dmin[j] = fminf(dmin[j], d); v = dmin[j]; }
      else v = d;
      if (v > bv) { bv = v; bi = j * TPB + t; }   // strict > keeps lowest index
    }
    {
      float acc = aL.x + aL.y;
      float d = fmaf(-2.f, acc, nl) + curN;
      float v;
      if (update) { dminL = fminf(dminL, d); v = dminL; }
      else v = d;
      if (v > bv) { bv = v; bi = NREG + t; }
    }
    unsigned long long k =
        ((unsigned long long)fmap(bv) << 12) | (unsigned)(4095 - bi);
#pragma unroll
    for (int off = 1; off < 64; off <<= 1) {
      unsigned long long ko = shfl_xor_u64(k, off);
      if (ko > k) k = ko;
    }
    return k;
  };

  // ---- round 0: barycenter (additive shift irrelevant for argmax; no dmin update) ----
  {
    float cs[C_];
#pragma unroll
    for (int d = 0; d < C_; ++d) cs[d] = rfl(cf0[d]);
    unsigned long long k = eval(cs, 0.f, false);
    if ((t & 63) == 0) redK[0][t >> 6] = k;
  }
  __syncthreads();

  // ---- main loop: 1 barrier per iteration, double-buffered reduce slots ----
  for (int it = 0; it < M_; ++it) {
    int rb = it & 1;
    unsigned long long k = redK[rb][0];
#pragma unroll
    for (int w = 1; w < NWAVES; ++w) {
      unsigned long long kw = redK[rb][w];
      if (kw > k) k = kw;
    }
    int jsel = 4095 - (int)(k & 4095ull);
    if (t == 0) idx_ws[blk * M_ + it] = jsel;
    // owner kills its dmin slot (never re-select) — static indices only
    if (jsel < NREG) {
      if ((jsel & (TPB - 1)) == t) {
        int j = jsel >> 10;
        if (j == 0) dmin[0] = -3e38f;
        else if (j == 1) dmin[1] = -3e38f;
        else dmin[2] = -3e38f;
      }
    } else {
      if (jsel - NREG == t) dminL = -3e38f;
    }
    if (it == M_ - 1) break;
    // uniform index -> SGPR-resident centroid + norm (scalar loads)
    int jsu = __builtin_amdgcn_readfirstlane(jsel);
    float curN = rfl(nrm[jsu]);
    const float* cf = evb + (size_t)jsu * C_;
    float cs[C_];
#pragma unroll
    for (int d = 0; d < C_; ++d) cs[d] = rfl(cf[d]);
    unsigned long long kk = eval(cs, curN, true);
    if ((t & 63) == 0) redK[rb ^ 1][t >> 6] = kk;
    __syncthreads();
  }
}

// ---------------- kernel 2: finalize (256 threads per batch) ----------------
// fps() returns selections in ASCENDING ORIGINAL-INDEX order (masked_select);
// rank-sort each run's indices before zipping along m (pairing matters).
// PRJ[0]=pe (ev-run pts @ Wpe), PRJ[1]=km (k-run pts @ Wk), PRJ[2]=vm (v-run @ Wv).
__global__ __launch_bounds__(256, 1) void finalize_kernel(
    const float* __restrict__ ev, const float* __restrict__ Wk,
    const float* __restrict__ Wv, const float* __restrict__ Wpe,
    const float* __restrict__ Wsa1, const float* __restrict__ Wsa2,
    const int* __restrict__ idx_ws, const float* __restrict__ partials,
    float* __restrict__ outvec_ws) {
  const int b = blockIdx.x;
  const int t = threadIdx.x;           // 256 threads = 4 waves
  const float* evb = ev + (size_t)b * N_ * C_;

  __shared__ float Wl[3][CN_][C_];        // 24 KB: Wpe, Wk, Wv
  __shared__ float W1l[CN_];
  __shared__ float W2l[C_][CN_ + 1];      // padded: conflict-free per-lane rows
  __shared__ int   lidx[3][M_], sidx[3][M_];
  __shared__ float XP[3][M_][C_];         // 24 KB selected rows
  __shared__ float PRJ[3][M_][CN_ + 1];   // padded
  __shared__ float sumx[C_], Pl[CN_], sl[M_], TP[4][CN_];

  // ---- stage weights ----
  {
    const float* Ws[3] = {Wpe, Wk, Wv};
#pragma unroll
    for (int r = 0; r < 3; ++r)
      for (int i = t; i < CN_ * C_ / 4; i += 256)
        ((float4*)&Wl[r][0][0])[i] = ((const float4*)Ws[r])[i];
    if (t < CN_) W1l[t] = Wsa1[t];
    for (int i = t; i < C_ * CN_; i += 256)
      W2l[i >> 6][i & 63] = Wsa2[i];      // scalar (padded dest not f4-aligned)
  }
  if (t < 192) {
    int r = t >> 6, mm = t & 63;
    lidx[r][mm] = idx_ws[(b * 3 + r) * M_ + mm];
  }
  if (t < C_) {
    float s = 0.f;
#pragma unroll
    for (int c = 0; c < NCHUNK; ++c) s += partials[((size_t)b * NCHUNK + c) * C_ + t];
    sumx[t] = s;
  }
  __syncthreads();
  if (t < 192) {       // parallel rank-sort: 3 runs × 64 slots
    int r = t >> 6, mm = t & 63;
    int my = lidx[r][mm];
    int rank = 0;
#pragma unroll
    for (int j = 0; j < M_; ++j)
      rank += (lidx[r][j] < my) || (lidx[r][j] == my && j < mm);
    sidx[r][rank] = my;
  }
  __syncthreads();
  // ---- stage selected rows: 192 rows × 8 quads ----
  for (int g = t; g < 3 * M_ * 8; g += 256) {
    int row = g >> 3, q = g & 7;
    int r = row >> 6, m = row & 63;
    int pi = sidx[r][m];
    *(float4*)&XP[r][m][q * 4] = ((const float4*)(evb + (size_t)pi * C_))[q];
  }
  __syncthreads();
  // ---- projections: wave r handles run r (lane = cn, W row in regs, x broadcast) ----
  {
    int w = t >> 6, cn = t & 63;
    if (w < 3) {
      float wr[C_];
#pragma unroll
      for (int q = 0; q < C_ / 4; ++q) {
        float4 v = *(const float4*)&Wl[w][cn][q * 4];
        wr[q * 4 + 0] = v.x; wr[q * 4 + 1] = v.y;
        wr[q * 4 + 2] = v.z; wr[q * 4 + 3] = v.w;
      }
      for (int m = 0; m < M_; ++m) {
        float2 a = make_float2(0.f, 0.f);
#pragma unroll
        for (int q = 0; q < C_ / 4; ++q) {
          float4 x = *(const float4*)&XP[w][m][q * 4];   // wave-broadcast read
          pkfma(a, x.x, x.y, wr[q * 4 + 0], wr[q * 4 + 1]);
          pkfma(a, x.z, x.w, wr[q * 4 + 2], wr[q * 4 + 3]);
        }
        PRJ[w][m][cn] = a.x + a.y;
      }
    } else {
      // Pl[cn] = (Σ_n ev) @ Wpe^T
      float a = 0.f;
#pragma unroll
      for (int c = 0; c < C_; ++c) a = fmaf(sumx[c], Wl[0][cn][c], a);
      Pl[cn] = a;
    }
  }
  __syncthreads();
  // ---- logits + softmax: wave 0, lane m ----
  if (t < 64) {
    float cm = 0.f;
#pragma unroll 8
    for (int cn = 0; cn < CN_; ++cn)
      cm = fmaf(PRJ[1][t][cn] + PRJ[0][t][cn], W1l[cn], cm);
    float lg = -cm;
    float mx = lg;
#pragma unroll
    for (int off = 32; off; off >>= 1) mx = fmaxf(mx, __shfl_xor(mx, off));
    float e = expf(lg - mx);
    float ssum = e;
#pragma unroll
    for (int off = 32; off; off >>= 1) ssum += __shfl_xor(ssum, off);
    sl[t] = e / ssum;
  }
  __syncthreads();
  // ---- tvec partials: thread (cn = t&63, quarter h = t>>6) ----
  {
    int cn = t & 63, h = t >> 6;
    float a = 0.f;
#pragma unroll
    for (int i = 0; i < 16; ++i) {
      int mm = h * 16 + i;
      a = fmaf(sl[mm],
               fmaf((float)N_, PRJ[2][mm][cn], Pl[cn]) - (float)N_ * PRJ[0][mm][cn],
               a);
    }
    TP[h][cn] = a;
  }
  __syncthreads();
  if (t < C_) {
    float o = 0.f;
#pragma unroll 8
    for (int cn = 0; cn < CN_; ++cn) {
      float tv = TP[0][cn] + TP[1][cn] + TP[2][cn] + TP[3][cn];
      o = fmaf(tv, W2l[t][cn], o);
    }
    outvec_ws[b * C_ + t] = o;
  }
}

// ---------------- kernel 3: broadcast out[b][n][:] = outvec[b][:] ----------------
__global__ void bcast_kernel(const float* __restrict__ outvec_ws,
                             float4* __restrict__ out) {
  int i = blockIdx.x * 256 + threadIdx.x;   // < 4*4096*8
  int b = i >> 15;
  int j = i & 7;
  const float4* ov = (const float4*)outvec_ws;
  out[i] = ov[b * 8 + j];
}

extern "C" void kernel_launch(void* const* d_in, const int* in_sizes, int n_in,
                              void* d_out, int out_size, void* d_ws, size_t ws_size,
                              hipStream_t stream) {
  const float* ev   = (const float*)d_in[0];
  // d_in[1] = W_qs: provably unused (a_n cancels in softmax over m)
  const float* Wk   = (const float*)d_in[2];
  const float* Wv   = (const float*)d_in[3];
  const float* Wpe  = (const float*)d_in[4];
  const float* Wsa1 = (const float*)d_in[5];
  const float* Wsa2 = (const float*)d_in[6];
  float* out = (float*)d_out;

  char* ws = (char*)d_ws;
  int*   idx    = (int*)ws;                     // 12*64*4        = 3072 B
  float* parts  = (float*)(ws + 3072);          // 4*16*32*4      = 8192 B
  float* outvec = (float*)(ws + 11264);         // 4*32*4         = 512 B
  float* nrm    = (float*)(ws + 11776);         // 12*4096*4      = 196608 B
  float* zall   = (float*)(ws + 208384);        // 12*4096*32*4   = 6291456 B

  norms_kernel   <<<dim3(192), dim3(NTPB), 0, stream>>>(ev, Wk, Wv, nrm, zall, parts);
  fps_kernel     <<<dim3(12),  dim3(TPB),  0, stream>>>(ev, nrm, zall, parts, idx);
  finalize_kernel<<<dim3(4),   dim3(256),  0, stream>>>(ev, Wk, Wv, Wpe, Wsa1, Wsa2,
                                                        idx, parts, outvec);
  bcast_kernel   <<<dim3(512), dim3(256),  0, stream>>>(outvec, (float4*)out);
}